// Round 6
// baseline (45.101 us; speedup 1.0000x reference)
//
#include <hip/hip_runtime.h>

typedef _Float16 f16;
typedef _Float16 f16x8 __attribute__((ext_vector_type(8)));
typedef float    f32x4 __attribute__((ext_vector_type(4)));

// Weight-fragment LDS layout (f16):
//   WF1: [5 nt][64 lane][8 j]  = 2560   (GEMM1 B: W1T, K 20->32)
//   WF2: [3 ks][3 nt][64][8]   = 4608   (GEMM2 B: W2T, K 80->96, N 40->48)
//   WF3: [2 ks][2 nt][64][8]   = 2048   (GEMM3 B: W3T, K 40->64, N 21->32)
#define WF1_OFF 0
#define WF2_OFF 2560
#define WF3_OFF 7168
#define WF_TOTAL 9216
#define WAVES 4

// One block = 64 events. Phase 1: VALU scores straight from x into an LDS
// A-tile. Phase 2: fused 3-GEMM f16 MFMA chain (layout verified in round 5).
// Fragment k-map convention: lane l supplies k = (l>>4)*8 + j for both A and
// B fragments (contraction invariant to the HW's intra-lane k-permutation).
// C/D layout: col = lane&15, row = (lane>>4)*4 + r (m89-verified).
__global__ __launch_bounds__(256) void fused_kernel(
    const float* __restrict__ x,    // [N*20*12]
    const float* __restrict__ Wl,   // [12,2]
    const float* __restrict__ bl,   // [2]
    const float* __restrict__ W1,   // [80,20]
    const float* __restrict__ b1,   // [80]
    const float* __restrict__ W2,   // [40,80]
    const float* __restrict__ b2,   // [40]
    const float* __restrict__ W3,   // [21,40]
    const float* __restrict__ b3,   // [21]
    float* __restrict__ out,        // [N,21]
    int n)
{
    __shared__ __align__(16) f16 wfl[WF_TOTAL];
    __shared__ __align__(16) f16 s_lds[64][40];          // scores, pitch 40
    __shared__ __align__(16) f16 h1t[WAVES][12][16][8];  // K 0..95 (80..95 = 0)
    __shared__ __align__(16) f16 h2t[WAVES][8][16][8];   // K 0..63 (40..63 = 0)

    const int tid  = threadIdx.x;
    const int wave = tid >> 6;
    const int lane = tid & 63;
    const int lrow = lane & 15;   // A row (event) / B,C col
    const int lg   = lane >> 4;   // k-group / C row-group

    // ---- build weight fragments directly from global (L2-resident) ----
#pragma unroll
    for (int it = 0; it < 10; ++it) {
        int idx = it * 256 + tid;                         // 2560
        int j = idx & 7, l = (idx >> 3) & 63, nt = idx >> 9;
        int nn = nt * 16 + (l & 15);
        int k  = (l >> 4) * 8 + j;
        wfl[WF1_OFF + idx] = (k < 20) ? (f16)W1[nn * 20 + k] : (f16)0.f;
    }
#pragma unroll
    for (int it = 0; it < 18; ++it) {
        int idx = it * 256 + tid;                         // 4608
        int j = idx & 7, l = (idx >> 3) & 63, grp = idx >> 9;
        int nt = grp % 3, ks = grp / 3;
        int nn = nt * 16 + (l & 15);
        int k  = ks * 32 + (l >> 4) * 8 + j;
        wfl[WF2_OFF + idx] = (k < 80 && nn < 40) ? (f16)W2[nn * 80 + k] : (f16)0.f;
    }
#pragma unroll
    for (int it = 0; it < 8; ++it) {
        int idx = it * 256 + tid;                         // 2048
        int j = idx & 7, l = (idx >> 3) & 63, grp = idx >> 9;
        int nt = grp & 1, ks = grp >> 1;
        int nn = nt * 16 + (l & 15);
        int k  = ks * 32 + (l >> 4) * 8 + j;
        wfl[WF3_OFF + idx] = (k < 40 && nn < 21) ? (f16)W3[nn * 40 + k] : (f16)0.f;
    }

    // zero the h-tile K-pad blocks
    {
        int* z1 = reinterpret_cast<int*>(&h1t[wave][10][0][0]);  // gg 10,11
        z1[lane] = 0; z1[lane + 64] = 0;
        int* z2 = reinterpret_cast<int*>(&h2t[wave][5][0][0]);   // gg 5,6,7
        z2[lane] = 0; z2[lane + 64] = 0; z2[lane + 128] = 0;
    }

    // ---- phase 1: triplet scores -> s_lds ----
    float wl[12];
#pragma unroll
    for (int f = 0; f < 12; ++f) wl[f] = Wl[f * 2 + 1];
    const float blv = bl[1];

    const int n_trip = n * 20;
    const int trip0 = blockIdx.x * 1280 + tid * 5;        // 5 triplets/thread
#pragma unroll
    for (int tt = 0; tt < 5; ++tt) {
        const int trip = trip0 + tt;
        if (trip < n_trip) {
            const float4* xt = reinterpret_cast<const float4*>(x + (size_t)trip * 12);
            float4 a0 = xt[0], a1 = xt[1], a2 = xt[2];
            float acc = blv;
            acc += a0.x*wl[0] + a0.y*wl[1] + a0.z*wl[2]  + a0.w*wl[3];
            acc += a1.x*wl[4] + a1.y*wl[5] + a1.z*wl[6]  + a1.w*wl[7];
            acc += a2.x*wl[8] + a2.y*wl[9] + a2.z*wl[10] + a2.w*wl[11];
            const int bt = tid * 5 + tt;                  // block-local triplet
            s_lds[bt / 20][bt % 20] = (f16)acc;
        }
    }
    // zero score K-pad cols 20..31
#pragma unroll
    for (int it = 0; it < 3; ++it) {
        int idx = it * 256 + tid;                         // 768
        s_lds[idx / 12][20 + idx % 12] = (f16)0.f;
    }

    __syncthreads();

    const int ev0 = blockIdx.x * (WAVES * 16) + wave * 16;
    if (ev0 >= n) return;   // n % 16 == 0 -> wave fully valid or fully out

    const f16x8* bfrag = reinterpret_cast<const f16x8*>(wfl);
    const f32x4 zero4 = {0.f, 0.f, 0.f, 0.f};

    // ---- GEMM1: [16 ev x 32k] x [32k x 80] ----
    f16x8 a1 = *reinterpret_cast<const f16x8*>(&s_lds[wave * 16 + lrow][lg * 8]);
    f32x4 acc1[5];
#pragma unroll
    for (int nt = 0; nt < 5; ++nt)
        acc1[nt] = __builtin_amdgcn_mfma_f32_16x16x32_f16(
            a1, bfrag[(WF1_OFF / 8) + nt * 64 + lane], zero4, 0, 0, 0);
#pragma unroll
    for (int nt = 0; nt < 5; ++nt) {
        const int neuron = nt * 16 + lrow;
        const float bias = b1[neuron];
#pragma unroll
        for (int r = 0; r < 4; ++r) {
            float v = fmaxf(acc1[nt][r] + bias, 0.f);
            h1t[wave][neuron >> 3][lg * 4 + r][neuron & 7] = (f16)v;
        }
    }
    // wave-private tile: compiler's lgkmcnt ordering suffices, no barrier

    // ---- GEMM2: [16 x 96k] x [96k x 48] ----
    f32x4 acc2[3] = {zero4, zero4, zero4};
#pragma unroll
    for (int ks = 0; ks < 3; ++ks) {
        f16x8 a = *reinterpret_cast<const f16x8*>(&h1t[wave][ks * 4 + lg][lrow][0]);
#pragma unroll
        for (int nt = 0; nt < 3; ++nt)
            acc2[nt] = __builtin_amdgcn_mfma_f32_16x16x32_f16(
                a, bfrag[(WF2_OFF / 8) + (ks * 3 + nt) * 64 + lane], acc2[nt], 0, 0, 0);
    }
#pragma unroll
    for (int nt = 0; nt < 3; ++nt) {
        const int nn = nt * 16 + lrow;
        const float bias = (nn < 40) ? b2[nn] : 0.f;
#pragma unroll
        for (int r = 0; r < 4; ++r) {
            float v = fmaxf(acc2[nt][r] + bias, 0.f);
            if (nn < 40) h2t[wave][nn >> 3][lg * 4 + r][nn & 7] = (f16)v;
        }
    }

    // ---- GEMM3: [16 x 64k] x [64k x 32] ----
    f32x4 acc3[2] = {zero4, zero4};
#pragma unroll
    for (int ks = 0; ks < 2; ++ks) {
        f16x8 a = *reinterpret_cast<const f16x8*>(&h2t[wave][ks * 4 + lg][lrow][0]);
#pragma unroll
        for (int nt = 0; nt < 2; ++nt)
            acc3[nt] = __builtin_amdgcn_mfma_f32_16x16x32_f16(
                a, bfrag[(WF3_OFF / 8) + (ks * 2 + nt) * 64 + lane], acc3[nt], 0, 0, 0);
    }
#pragma unroll
    for (int nt = 0; nt < 2; ++nt) {
        const int col = nt * 16 + lrow;
        if (col < 21) {
            const float bias = b3[col];
#pragma unroll
            for (int r = 0; r < 4; ++r)
                out[(size_t)(ev0 + lg * 4 + r) * 21 + col] = acc3[nt][r] + bias;
        }
    }
}

extern "C" void kernel_launch(void* const* d_in, const int* in_sizes, int n_in,
                              void* d_out, int out_size, void* d_ws, size_t ws_size,
                              hipStream_t stream) {
    const float* x  = (const float*)d_in[0];
    const float* Wl = (const float*)d_in[1];
    const float* bl = (const float*)d_in[2];
    const float* W1 = (const float*)d_in[3];
    const float* b1 = (const float*)d_in[4];
    const float* W2 = (const float*)d_in[5];
    const float* b2 = (const float*)d_in[6];
    const float* W3 = (const float*)d_in[7];
    const float* b3 = (const float*)d_in[8];
    float* out = (float*)d_out;

    const int n = in_sizes[0] / 240;       // events (100000)
    const int grid = (n + 63) / 64;        // 64 events per block
    fused_kernel<<<grid, 256, 0, stream>>>(x, Wl, bl, W1, b1, W2, b2, W3, b3,
                                           out, n);
}

// Round 7
// 32.669 us; speedup vs baseline: 1.3805x; 1.3805x over previous
//
#include <hip/hip_runtime.h>

typedef _Float16 f16;
typedef _Float16 f16x8 __attribute__((ext_vector_type(8)));
typedef float    f32x4 __attribute__((ext_vector_type(4)));

// Weight-fragment buffer (f16, built once by prep_kernel in d_ws):
//   WF1: [5 nt][64 lane][8 j] = 2560  (GEMM1 B: W1T, K 20->32; k==20 carries b1)
//   WF2: [3 ks][3 nt][64][8]  = 4608  (GEMM2 B: W2T, K 80->96, N 40->48; k==80 carries b2)
//   WF3: [2 ks][2 nt][64][8]  = 2048  (GEMM3 B: W3T, K 40->64, N 21->32; k==40 carries b3)
#define WF1_OFF 0
#define WF2_OFF 2560
#define WF3_OFF 7168
#define WF_TOTAL 9216
#define WAVES 4

// Fragment k-map convention: lane l supplies k = (l>>4)*8 + j for BOTH A and B
// fragments (contraction invariant to HW intra-lane k-permutation).
// C/D layout (m89-verified, confirmed rounds 5/6): col = lane&15, row = (lane>>4)*4 + r.
__global__ void prep_kernel(const float* __restrict__ W1, const float* __restrict__ b1,
                            const float* __restrict__ W2, const float* __restrict__ b2,
                            const float* __restrict__ W3, const float* __restrict__ b3,
                            f16* __restrict__ wf) {
    const int t0 = blockIdx.x * blockDim.x + threadIdx.x;
    const int stride = gridDim.x * blockDim.x;
    for (int idx = t0; idx < 5 * 512; idx += stride) {
        int j = idx & 7, l = (idx >> 3) & 63, nt = idx >> 9;
        int nn = nt * 16 + (l & 15);
        int k  = (l >> 4) * 8 + j;
        float v = (k < 20) ? W1[nn * 20 + k] : (k == 20 ? b1[nn] : 0.f);
        wf[WF1_OFF + idx] = (f16)v;
    }
    for (int idx = t0; idx < 9 * 512; idx += stride) {
        int j = idx & 7, l = (idx >> 3) & 63, grp = idx >> 9;
        int nt = grp % 3, ks = grp / 3;
        int nn = nt * 16 + (l & 15);
        int k  = ks * 32 + (l >> 4) * 8 + j;
        float v = 0.f;
        if (nn < 40) { if (k < 80) v = W2[nn * 80 + k]; else if (k == 80) v = b2[nn]; }
        wf[WF2_OFF + idx] = (f16)v;
    }
    for (int idx = t0; idx < 4 * 512; idx += stride) {
        int j = idx & 7, l = (idx >> 3) & 63, grp = idx >> 9;
        int nt = grp & 1, ks = grp >> 1;
        int nn = nt * 16 + (l & 15);
        int k  = ks * 32 + (l >> 4) * 8 + j;
        float v = 0.f;
        if (nn < 21) { if (k < 40) v = W3[nn * 40 + k]; else if (k == 40) v = b3[nn]; }
        wf[WF3_OFF + idx] = (f16)v;
    }
}

// One block = 64 events. Phase 1: coalesced wf->LDS copy + VALU scores from x
// (lane stride 48B, round-2-proven pattern). Phase 2: fused 3-GEMM f16 MFMA.
__global__ __launch_bounds__(256) void fused_kernel(
    const float* __restrict__ x,    // [N*20*12]
    const float* __restrict__ Wl,   // [12,2]
    const float* __restrict__ bl,   // [2]
    const f16*   __restrict__ wf,   // [WF_TOTAL]
    float* __restrict__ out,        // [N,21]
    int n)
{
    __shared__ __align__(16) f16 wfl[WF_TOTAL];
    __shared__ __align__(16) f16 s_lds[64][40];          // scores; col20=1.0 (bias), 21..31=0
    __shared__ __align__(16) f16 h1t[WAVES][12][16][8];  // K 0..95; k==80 row = 1.0
    __shared__ __align__(16) f16 h2t[WAVES][8][16][8];   // K 0..63; k==40 row = 1.0

    const int tid  = threadIdx.x;
    const int wave = tid >> 6;
    const int lane = tid & 63;
    const int lrow = lane & 15;   // A row (event) / B,C col
    const int lg   = lane >> 4;   // k-group / C row-group

    // ---- coalesced weight-fragment copy: 1152 x uint4 from L2 ----
    {
        const uint4* src = reinterpret_cast<const uint4*>(wf);
        uint4* dst = reinterpret_cast<uint4*>(wfl);
        for (int idx = tid; idx < WF_TOTAL * 2 / 16; idx += 256)
            dst[idx] = src[idx];
    }

    // ---- h-tile K-pad init: zeros + bias-row 1.0 (wave-private) ----
    {
        int* z1 = reinterpret_cast<int*>(&h1t[wave][10][0][0]);  // gg 10,11 (512B)
        z1[lane] = 0; z1[lane + 64] = 0;
        int* z2 = reinterpret_cast<int*>(&h2t[wave][5][0][0]);   // gg 5,6,7 (768B)
        z2[lane] = 0; z2[lane + 64] = 0; z2[lane + 128] = 0;
        if (lane < 16) {
            h1t[wave][10][lane][0] = (f16)1.f;   // k == 80
            h2t[wave][5][lane][0]  = (f16)1.f;   // k == 40
        }
    }

    // ---- score K-pad: col 20 = 1.0 (bias lane), 21..31 = 0, all 64 rows ----
#pragma unroll
    for (int it = 0; it < 3; ++it) {
        int idx = it * 256 + tid;                // 768 = 64 rows x 12 cols
        int row = idx / 12, c = idx % 12;
        s_lds[row][20 + c] = (c == 0) ? (f16)1.f : (f16)0.f;
    }

    // ---- phase 1: triplet scores, lane-stride-48B loads ----
    float wl[12];
#pragma unroll
    for (int f = 0; f < 12; ++f) wl[f] = Wl[f * 2 + 1];
    const float blv = bl[1];

    const int n_trip = n * 20;
    const int trip_base = blockIdx.x * 1280;
#pragma unroll
    for (int r = 0; r < 5; ++r) {
        const int bt = r * 256 + tid;            // block-local triplet 0..1279
        const int trip = trip_base + bt;
        if (trip < n_trip) {
            const float4* xt = reinterpret_cast<const float4*>(x + (size_t)trip * 12);
            float4 a0 = xt[0], a1 = xt[1], a2 = xt[2];
            float acc = blv;
            acc += a0.x*wl[0] + a0.y*wl[1] + a0.z*wl[2]  + a0.w*wl[3];
            acc += a1.x*wl[4] + a1.y*wl[5] + a1.z*wl[6]  + a1.w*wl[7];
            acc += a2.x*wl[8] + a2.y*wl[9] + a2.z*wl[10] + a2.w*wl[11];
            s_lds[bt / 20][bt % 20] = (f16)acc;
        }
    }

    __syncthreads();

    const int ev0 = blockIdx.x * (WAVES * 16) + wave * 16;
    if (ev0 >= n) return;   // n % 16 == 0 -> wave fully valid or fully out

    const f16x8* bfrag = reinterpret_cast<const f16x8*>(wfl);
    const f32x4 zero4 = {0.f, 0.f, 0.f, 0.f};

    // ---- GEMM1: [16 ev x 32k] x [32k x 80]  (bias in k=20) ----
    f16x8 a1 = *reinterpret_cast<const f16x8*>(&s_lds[wave * 16 + lrow][lg * 8]);
    f32x4 acc1[5];
#pragma unroll
    for (int nt = 0; nt < 5; ++nt)
        acc1[nt] = __builtin_amdgcn_mfma_f32_16x16x32_f16(
            a1, bfrag[(WF1_OFF / 8) + nt * 64 + lane], zero4, 0, 0, 0);
#pragma unroll
    for (int nt = 0; nt < 5; ++nt) {
        const int neuron = nt * 16 + lrow;
#pragma unroll
        for (int r = 0; r < 4; ++r) {
            float v = fmaxf(acc1[nt][r], 0.f);
            h1t[wave][neuron >> 3][lg * 4 + r][neuron & 7] = (f16)v;
        }
    }
    // wave-private tile: same-wave DS ordering + compiler lgkmcnt suffice (rounds 5/6 verified)

    // ---- GEMM2: [16 x 96k] x [96k x 48]  (bias in k=80) ----
    f32x4 acc2[3] = {zero4, zero4, zero4};
#pragma unroll
    for (int ks = 0; ks < 3; ++ks) {
        f16x8 a = *reinterpret_cast<const f16x8*>(&h1t[wave][ks * 4 + lg][lrow][0]);
#pragma unroll
        for (int nt = 0; nt < 3; ++nt)
            acc2[nt] = __builtin_amdgcn_mfma_f32_16x16x32_f16(
                a, bfrag[(WF2_OFF / 8) + (ks * 3 + nt) * 64 + lane], acc2[nt], 0, 0, 0);
    }
#pragma unroll
    for (int nt = 0; nt < 3; ++nt) {
        const int nn = nt * 16 + lrow;
#pragma unroll
        for (int r = 0; r < 4; ++r) {
            float v = fmaxf(acc2[nt][r], 0.f);
            if (nn < 40) h2t[wave][nn >> 3][lg * 4 + r][nn & 7] = (f16)v;
        }
    }

    // ---- GEMM3: [16 x 64k] x [64k x 32]  (bias in k=40) ----
    f32x4 acc3[2] = {zero4, zero4};
#pragma unroll
    for (int ks = 0; ks < 2; ++ks) {
        f16x8 a = *reinterpret_cast<const f16x8*>(&h2t[wave][ks * 4 + lg][lrow][0]);
#pragma unroll
        for (int nt = 0; nt < 2; ++nt)
            acc3[nt] = __builtin_amdgcn_mfma_f32_16x16x32_f16(
                a, bfrag[(WF3_OFF / 8) + (ks * 2 + nt) * 64 + lane], acc3[nt], 0, 0, 0);
    }
#pragma unroll
    for (int nt = 0; nt < 2; ++nt) {
        const int col = nt * 16 + lrow;
        if (col < 21) {
#pragma unroll
            for (int r = 0; r < 4; ++r)
                out[(size_t)(ev0 + lg * 4 + r) * 21 + col] = acc3[nt][r];
        }
    }
}

extern "C" void kernel_launch(void* const* d_in, const int* in_sizes, int n_in,
                              void* d_out, int out_size, void* d_ws, size_t ws_size,
                              hipStream_t stream) {
    const float* x  = (const float*)d_in[0];
    const float* Wl = (const float*)d_in[1];
    const float* bl = (const float*)d_in[2];
    const float* W1 = (const float*)d_in[3];
    const float* b1 = (const float*)d_in[4];
    const float* W2 = (const float*)d_in[5];
    const float* b2 = (const float*)d_in[6];
    const float* W3 = (const float*)d_in[7];
    const float* b3 = (const float*)d_in[8];
    float* out = (float*)d_out;

    const int n = in_sizes[0] / 240;       // events (100000)
    f16* wf = (f16*)d_ws;                  // [WF_TOTAL] f16 = 18 KB

    prep_kernel<<<16, 256, 0, stream>>>(W1, b1, W2, b2, W3, b3, wf);

    const int grid = (n + 63) / 64;        // 64 events per block
    fused_kernel<<<grid, 256, 0, stream>>>(x, Wl, bl, wf, out, n);
}

// Round 8
// 29.060 us; speedup vs baseline: 1.5520x; 1.1242x over previous
//
#include <hip/hip_runtime.h>

typedef _Float16 f16;
typedef _Float16 f16x8 __attribute__((ext_vector_type(8)));
typedef float    f32x4 __attribute__((ext_vector_type(4)));

// Weight-fragment buffer (f16, built once by prep_kernel in d_ws).
// 18 KB total -> fits in each CU's 32 KB L1; MFMA B-operands are read
// DIRECTLY from global (L1-hot, 1KB contiguous per fragment) — no LDS staging.
//   WF1: [5 nt][64 lane][8 j] = 2560  (GEMM1 B: W1T, K 20->32; k==20 carries b1)
//   WF2: [3 ks][3 nt][64][8]  = 4608  (GEMM2 B: W2T, K 80->96, N 40->48; k==80 carries b2)
//   WF3: [2 ks][2 nt][64][8]  = 2048  (GEMM3 B: W3T, K 40->64, N 21->32; k==40 carries b3)
#define WF1_OFF 0
#define WF2_OFF 2560
#define WF3_OFF 7168
#define WF_TOTAL 9216
#define WAVES 4

// Fragment k-map convention: lane l supplies k = (l>>4)*8 + j for BOTH A and B
// fragments (contraction invariant to HW intra-lane k-permutation).
// C/D layout (m89-verified, confirmed rounds 5-7): col = lane&15, row = (lane>>4)*4 + r.
__global__ void prep_kernel(const float* __restrict__ W1, const float* __restrict__ b1,
                            const float* __restrict__ W2, const float* __restrict__ b2,
                            const float* __restrict__ W3, const float* __restrict__ b3,
                            f16* __restrict__ wf) {
    const int t0 = blockIdx.x * blockDim.x + threadIdx.x;
    const int stride = gridDim.x * blockDim.x;
    for (int idx = t0; idx < 5 * 512; idx += stride) {
        int j = idx & 7, l = (idx >> 3) & 63, nt = idx >> 9;
        int nn = nt * 16 + (l & 15);
        int k  = (l >> 4) * 8 + j;
        float v = (k < 20) ? W1[nn * 20 + k] : (k == 20 ? b1[nn] : 0.f);
        wf[WF1_OFF + idx] = (f16)v;
    }
    for (int idx = t0; idx < 9 * 512; idx += stride) {
        int j = idx & 7, l = (idx >> 3) & 63, grp = idx >> 9;
        int nt = grp % 3, ks = grp / 3;
        int nn = nt * 16 + (l & 15);
        int k  = ks * 32 + (l >> 4) * 8 + j;
        float v = 0.f;
        if (nn < 40) { if (k < 80) v = W2[nn * 80 + k]; else if (k == 80) v = b2[nn]; }
        wf[WF2_OFF + idx] = (f16)v;
    }
    for (int idx = t0; idx < 4 * 512; idx += stride) {
        int j = idx & 7, l = (idx >> 3) & 63, grp = idx >> 9;
        int nt = grp & 1, ks = grp >> 1;
        int nn = nt * 16 + (l & 15);
        int k  = ks * 32 + (l >> 4) * 8 + j;
        float v = 0.f;
        if (nn < 21) { if (k < 40) v = W3[nn * 40 + k]; else if (k == 40) v = b3[nn]; }
        wf[WF3_OFF + idx] = (f16)v;
    }
}

// One block = 64 events, 25.3 KB LDS -> 6 blocks/CU.
// Phase 1: VALU scores from x (lane stride 48B). Phase 2: fused 3-GEMM f16 MFMA,
// B-fragments straight from L1-resident global wf.
__global__ __launch_bounds__(256) void fused_kernel(
    const float* __restrict__ x,    // [N*20*12]
    const float* __restrict__ Wl,   // [12,2]
    const float* __restrict__ bl,   // [2]
    const f16*   __restrict__ wf,   // [WF_TOTAL]
    float* __restrict__ out,        // [N,21]
    int n)
{
    __shared__ __align__(16) f16 s_lds[64][40];          // scores; col20=1.0 (bias), 21..31=0
    __shared__ __align__(16) f16 h1t[WAVES][12][16][8];  // K 0..95; k==80 row = 1.0
    __shared__ __align__(16) f16 h2t[WAVES][8][16][8];   // K 0..63; k==40 row = 1.0

    const int tid  = threadIdx.x;
    const int wave = tid >> 6;
    const int lane = tid & 63;
    const int lrow = lane & 15;   // A row (event) / B,C col
    const int lg   = lane >> 4;   // k-group / C row-group

    // ---- h-tile K-pad init: zeros + bias-row 1.0 (wave-private) ----
    {
        int* z1 = reinterpret_cast<int*>(&h1t[wave][10][0][0]);  // gg 10,11 (512B)
        z1[lane] = 0; z1[lane + 64] = 0;
        int* z2 = reinterpret_cast<int*>(&h2t[wave][5][0][0]);   // gg 5,6,7 (768B)
        z2[lane] = 0; z2[lane + 64] = 0; z2[lane + 128] = 0;
        if (lane < 16) {
            h1t[wave][10][lane][0] = (f16)1.f;   // k == 80
            h2t[wave][5][lane][0]  = (f16)1.f;   // k == 40
        }
    }

    // ---- score K-pad: col 20 = 1.0 (bias lane), 21..31 = 0, all 64 rows ----
#pragma unroll
    for (int it = 0; it < 3; ++it) {
        int idx = it * 256 + tid;                // 768 = 64 rows x 12 cols
        int row = idx / 12, c = idx % 12;
        s_lds[row][20 + c] = (c == 0) ? (f16)1.f : (f16)0.f;
    }

    // ---- phase 1: triplet scores, lane-stride-48B loads ----
    float wl[12];
#pragma unroll
    for (int f = 0; f < 12; ++f) wl[f] = Wl[f * 2 + 1];
    const float blv = bl[1];

    const int n_trip = n * 20;
    const int trip_base = blockIdx.x * 1280;
#pragma unroll
    for (int r = 0; r < 5; ++r) {
        const int bt = r * 256 + tid;            // block-local triplet 0..1279
        const int trip = trip_base + bt;
        if (trip < n_trip) {
            const float4* xt = reinterpret_cast<const float4*>(x + (size_t)trip * 12);
            float4 a0 = xt[0], a1 = xt[1], a2 = xt[2];
            float acc = blv;
            acc += a0.x*wl[0] + a0.y*wl[1] + a0.z*wl[2]  + a0.w*wl[3];
            acc += a1.x*wl[4] + a1.y*wl[5] + a1.z*wl[6]  + a1.w*wl[7];
            acc += a2.x*wl[8] + a2.y*wl[9] + a2.z*wl[10] + a2.w*wl[11];
            s_lds[bt / 20][bt % 20] = (f16)acc;
        }
    }

    __syncthreads();

    const int ev0 = blockIdx.x * (WAVES * 16) + wave * 16;
    if (ev0 >= n) return;   // n % 16 == 0 -> wave fully valid or fully out

    const f16x8* bfrag = reinterpret_cast<const f16x8*>(wf);   // global, L1-hot
    const f32x4 zero4 = {0.f, 0.f, 0.f, 0.f};

    // ---- GEMM1: [16 ev x 32k] x [32k x 80]  (bias in k=20) ----
    f16x8 a1 = *reinterpret_cast<const f16x8*>(&s_lds[wave * 16 + lrow][lg * 8]);
    f32x4 acc1[5];
#pragma unroll
    for (int nt = 0; nt < 5; ++nt)
        acc1[nt] = __builtin_amdgcn_mfma_f32_16x16x32_f16(
            a1, bfrag[(WF1_OFF / 8) + nt * 64 + lane], zero4, 0, 0, 0);
#pragma unroll
    for (int nt = 0; nt < 5; ++nt) {
        const int neuron = nt * 16 + lrow;
#pragma unroll
        for (int r = 0; r < 4; ++r) {
            float v = fmaxf(acc1[nt][r], 0.f);
            h1t[wave][neuron >> 3][lg * 4 + r][neuron & 7] = (f16)v;
        }
    }
    // wave-private tile: same-wave DS ordering + compiler lgkmcnt suffice (rounds 5-7 verified)

    // ---- GEMM2: [16 x 96k] x [96k x 48]  (bias in k=80) ----
    f32x4 acc2[3] = {zero4, zero4, zero4};
#pragma unroll
    for (int ks = 0; ks < 3; ++ks) {
        f16x8 a = *reinterpret_cast<const f16x8*>(&h1t[wave][ks * 4 + lg][lrow][0]);
#pragma unroll
        for (int nt = 0; nt < 3; ++nt)
            acc2[nt] = __builtin_amdgcn_mfma_f32_16x16x32_f16(
                a, bfrag[(WF2_OFF / 8) + (ks * 3 + nt) * 64 + lane], acc2[nt], 0, 0, 0);
    }
#pragma unroll
    for (int nt = 0; nt < 3; ++nt) {
        const int nn = nt * 16 + lrow;
#pragma unroll
        for (int r = 0; r < 4; ++r) {
            float v = fmaxf(acc2[nt][r], 0.f);
            if (nn < 40) h2t[wave][nn >> 3][lg * 4 + r][nn & 7] = (f16)v;
        }
    }

    // ---- GEMM3: [16 x 64k] x [64k x 32]  (bias in k=40) ----
    f32x4 acc3[2] = {zero4, zero4};
#pragma unroll
    for (int ks = 0; ks < 2; ++ks) {
        f16x8 a = *reinterpret_cast<const f16x8*>(&h2t[wave][ks * 4 + lg][lrow][0]);
#pragma unroll
        for (int nt = 0; nt < 2; ++nt)
            acc3[nt] = __builtin_amdgcn_mfma_f32_16x16x32_f16(
                a, bfrag[(WF3_OFF / 8) + (ks * 2 + nt) * 64 + lane], acc3[nt], 0, 0, 0);
    }
#pragma unroll
    for (int nt = 0; nt < 2; ++nt) {
        const int col = nt * 16 + lrow;
        if (col < 21) {
#pragma unroll
            for (int r = 0; r < 4; ++r)
                out[(size_t)(ev0 + lg * 4 + r) * 21 + col] = acc3[nt][r];
        }
    }
}

extern "C" void kernel_launch(void* const* d_in, const int* in_sizes, int n_in,
                              void* d_out, int out_size, void* d_ws, size_t ws_size,
                              hipStream_t stream) {
    const float* x  = (const float*)d_in[0];
    const float* Wl = (const float*)d_in[1];
    const float* bl = (const float*)d_in[2];
    const float* W1 = (const float*)d_in[3];
    const float* b1 = (const float*)d_in[4];
    const float* W2 = (const float*)d_in[5];
    const float* b2 = (const float*)d_in[6];
    const float* W3 = (const float*)d_in[7];
    const float* b3 = (const float*)d_in[8];
    float* out = (float*)d_out;

    const int n = in_sizes[0] / 240;       // events (100000)
    f16* wf = (f16*)d_ws;                  // [WF_TOTAL] f16 = 18 KB

    prep_kernel<<<16, 256, 0, stream>>>(W1, b1, W2, b2, W3, b3, wf);

    const int grid = (n + 63) / 64;        // 64 events per block
    fused_kernel<<<grid, 256, 0, stream>>>(x, Wl, bl, wf, out, n);
}